// Round 3
// baseline (219.759 us; speedup 1.0000x reference)
//
#include <hip/hip_runtime.h>

#define NT 256
#define RCHUNK 32
#define NSLOT 32

typedef float f4 __attribute__((ext_vector_type(4)));

__device__ __forceinline__ f4 bl4(__amdgpu_buffer_rsrc_t r, int voff) {
    auto d = __builtin_amdgcn_raw_buffer_load_b128(r, voff, 0, 0);
    return __builtin_bit_cast(f4, d);
}

__device__ __forceinline__ float ccval(float sI, float sJ, float sII, float sJJ,
                                       float sIJ, float inv_ws) {
    float cross = fmaf(-(sI * sJ), inv_ws, sIJ);
    float iv    = fmaf(-(sI * sI), inv_ws, sII);
    float jv    = fmaf(-(sJ * sJ), inv_ws, sJJ);
    float den   = fmaf(iv, jv, 1e-8f);
    return (cross * cross) * __builtin_amdgcn_rcpf(den);
}

// Each 64-lane wave owns a 128-col x RCHUNK-row tile (2 cols/lane).
// Horizontal 9/7/5-tap sums from direct buffer loads (OOB -> 0 via SRD bounds),
// vertical sliding window in a register ring with compile-time slots.
template<int W, int H, int WIN, int S>
__device__ __forceinline__ void level_wave(const float* __restrict__ yh,
                                           const float* __restrict__ y,
                                           int sub, float* __restrict__ ws_acc,
                                           int level)
{
    constexpr int HW = WIN / 2;
    constexpr int T  = RCHUNK + 2 * HW;
    constexpr int G  = (T + WIN - 1) / WIN;
    constexpr int SE = (-HW) & 3;            // elem shift, even lanes
    constexpr int SO = (2 - HW) & 3;         // elem shift, odd lanes
    constexpr int SMAX = SE > SO ? SE : SO;
    constexpr int NF4J = (WIN + 1 + SMAX + 3) / 4;
    constexpr int OFF = (S - 2) / 2;
    constexpr int SHI = (S <= 2) ? 0 : (OFF & 3);
    constexpr int NF4I = (S == 1) ? NF4J : (S * WIN + SHI + 2 + 3) / 4;
    constexpr float INV_WS = 1.0f / (float)(WIN * WIN);

    constexpr int STRIPS = (W + 127) / 128;
    constexpr int CHUNKS = H / RCHUNK;

    int b     = sub / (STRIPS * CHUNKS);
    int rem   = sub - b * (STRIPS * CHUNKS);
    int chunk = rem / STRIPS;
    int strip = rem - chunk * STRIPS;

    int r0 = __builtin_amdgcn_readfirstlane(chunk * RCHUNK);
    int bu = __builtin_amdgcn_readfirstlane(b);
    const float* Jb = yh + (size_t)bu * (W * H);
    const float* Yb = y  + (size_t)bu * (512 * 512);

    int l = threadIdx.x & 63;
    bool odd = (l & 1) != 0;
    int c0 = strip * 128;
    int ub = c0 + 2 * l - HW;                 // first col of the 2-window union
    int voffJ = (ub & ~3) * 4;                // 16B-aligned byte offset
    int voffI;
    if constexpr (S == 1) voffI = voffJ;
    else                  voffI = ((S * ub + OFF) & ~3) * 4;

    float rIA[WIN], rIB[WIN], rJA[WIN], rJB[WIN], rIIA[WIN], rIIB[WIN],
          rJJA[WIN], rJJB[WIN], rIJA[WIN], rIJB[WIN];
#pragma unroll
    for (int k = 0; k < WIN; ++k) {
        rIA[k] = 0.f; rIB[k] = 0.f; rJA[k] = 0.f; rJB[k] = 0.f;
        rIIA[k] = 0.f; rIIB[k] = 0.f; rJJA[k] = 0.f; rJJB[k] = 0.f;
        rIJA[k] = 0.f; rIJB[k] = 0.f;
    }
    float vIA=0.f, vIB=0.f, vJA=0.f, vJB=0.f, vIIA=0.f, vIIB=0.f,
          vJJA=0.f, vJJB=0.f, vIJA=0.f, vIJB=0.f;
    float l2acc = 0.f, ccacc = 0.f;

    for (int g = 0; g < G; ++g) {
#pragma unroll
        for (int u = 0; u < WIN; ++u) {
            int rr = g * WIN + u;
            int r  = r0 - HW + rr;
            bool valid = (r >= 0) && (r < H) && (rr < T);
            int nrecJ = valid ? W * 4 : 0;
            int nrecY = valid ? 512 * 4 : 0;

            float qJ[WIN + 1], qI[WIN + 1];
            {
                auto rJ = __builtin_amdgcn_make_buffer_rsrc(
                    (void*)(Jb + (long)r * W), (short)0, nrecJ, 0x00020000);
                float LJ[NF4J * 4];
#pragma unroll
                for (int k = 0; k < NF4J; ++k) {
                    f4 v = bl4(rJ, voffJ + 16 * k);
                    LJ[4*k+0] = v.x; LJ[4*k+1] = v.y; LJ[4*k+2] = v.z; LJ[4*k+3] = v.w;
                }
#pragma unroll
                for (int e = 0; e <= WIN; ++e)
                    qJ[e] = odd ? LJ[e + SO] : LJ[e + SE];
            }
            if constexpr (S == 1) {
                auto rI = __builtin_amdgcn_make_buffer_rsrc(
                    (void*)(Yb + (long)r * 512), (short)0, nrecY, 0x00020000);
                float LI[NF4J * 4];
#pragma unroll
                for (int k = 0; k < NF4J; ++k) {
                    f4 v = bl4(rI, voffI + 16 * k);
                    LI[4*k+0] = v.x; LI[4*k+1] = v.y; LI[4*k+2] = v.z; LI[4*k+3] = v.w;
                }
#pragma unroll
                for (int e = 0; e <= WIN; ++e)
                    qI[e] = odd ? LI[e + SO] : LI[e + SE];
            } else {
                int yr = S * r + OFF;
                float p[WIN + 1];
                {
                    auto rA = __builtin_amdgcn_make_buffer_rsrc(
                        (void*)(Yb + (long)yr * 512), (short)0, nrecY, 0x00020000);
                    float LA[NF4I * 4];
#pragma unroll
                    for (int k = 0; k < NF4I; ++k) {
                        f4 v = bl4(rA, voffI + 16 * k);
                        LA[4*k+0] = v.x; LA[4*k+1] = v.y; LA[4*k+2] = v.z; LA[4*k+3] = v.w;
                    }
#pragma unroll
                    for (int e = 0; e <= WIN; ++e)
                        p[e] = LA[S*e + SHI] + LA[S*e + SHI + 1];
                }
                {
                    auto rB = __builtin_amdgcn_make_buffer_rsrc(
                        (void*)(Yb + (long)(yr + 1) * 512), (short)0, nrecY, 0x00020000);
                    float LB[NF4I * 4];
#pragma unroll
                    for (int k = 0; k < NF4I; ++k) {
                        f4 v = bl4(rB, voffI + 16 * k);
                        LB[4*k+0] = v.x; LB[4*k+1] = v.y; LB[4*k+2] = v.z; LB[4*k+3] = v.w;
                    }
#pragma unroll
                    for (int e = 0; e <= WIN; ++e)
                        p[e] += LB[S*e + SHI] + LB[S*e + SHI + 1];
                }
#pragma unroll
                for (int e = 0; e <= WIN; ++e)
                    qI[e] = 0.25f * p[e];
            }

            // horizontal window sums: shared middle + two ends (windows A, B)
            float mI=0.f, mJ=0.f, mII=0.f, mJJ=0.f, mIJ=0.f;
#pragma unroll
            for (int e = 1; e < WIN; ++e) {
                mI += qI[e]; mJ += qJ[e];
                mII = fmaf(qI[e], qI[e], mII);
                mJJ = fmaf(qJ[e], qJ[e], mJJ);
                mIJ = fmaf(qI[e], qJ[e], mIJ);
            }
            float hIA = mI + qI[0],  hIB = mI + qI[WIN];
            float hJA = mJ + qJ[0],  hJB = mJ + qJ[WIN];
            float hIIA = fmaf(qI[0], qI[0], mII), hIIB = fmaf(qI[WIN], qI[WIN], mII);
            float hJJA = fmaf(qJ[0], qJ[0], mJJ), hJJB = fmaf(qJ[WIN], qJ[WIN], mJJ);
            float hIJA = fmaf(qI[0], qJ[0], mIJ), hIJB = fmaf(qI[WIN], qJ[WIN], mIJ);

            rIA[u]=hIA; rIB[u]=hIB; rJA[u]=hJA; rJB[u]=hJB;
            rIIA[u]=hIIA; rIIB[u]=hIIB; rJJA[u]=hJJA; rJJB[u]=hJJB;
            rIJA[u]=hIJA; rIJB[u]=hIJB;
            vIA+=hIA; vIB+=hIB; vJA+=hJA; vJB+=hJB; vIIA+=hIIA; vIIB+=hIIB;
            vJJA+=hJJA; vJJB+=hJJB; vIJA+=hIJA; vIJB+=hIJB;

            if (rr >= HW && rr < HW + RCHUNK) {
                float dA = qJ[HW] - qI[HW];
                float dB = qJ[HW + 1] - qI[HW + 1];
                l2acc = fmaf(dA, dA, l2acc);
                l2acc = fmaf(dB, dB, l2acc);
            }
            if (rr >= 2 * HW && rr < T) {
                ccacc += ccval(vIA, vJA, vIIA, vJJA, vIJA, INV_WS);
                ccacc += ccval(vIB, vJB, vIIB, vJJB, vIJB, INV_WS);
                const int uo = (u + 1) % WIN;   // compile-time after unroll
                vIA-=rIA[uo]; vIB-=rIB[uo]; vJA-=rJA[uo]; vJB-=rJB[uo];
                vIIA-=rIIA[uo]; vIIB-=rIIB[uo]; vJJA-=rJJA[uo]; vJJB-=rJJB[uo];
                vIJA-=rIJA[uo]; vIJB-=rIJB[uo];
            }
        }
    }

#pragma unroll
    for (int off = 32; off > 0; off >>= 1) {
        l2acc += __shfl_down(l2acc, off);
        ccacc += __shfl_down(ccacc, off);
    }
    if (l == 0) {
        int slot = sub & (NSLOT - 1);
        atomicAdd(&ws_acc[(level * 2 + 0) * NSLOT + slot], l2acc);
        atomicAdd(&ws_acc[(level * 2 + 1) * NSLOT + slot], ccacc);
    }
}

__global__ __launch_bounds__(NT)
void hier_loss_kernel(const float* __restrict__ yh0, const float* __restrict__ yh1,
                      const float* __restrict__ yh2, const float* __restrict__ yh3,
                      const float* __restrict__ y, float* ws_acc)
{
    int wid = blockIdx.x * (NT / 64) + (threadIdx.x >> 6);
    // L0: 4 strips x 16 chunks x 32 = 2048 waves
    // L1: 2 x 8 x 32 = 512  -> [2048, 2560)
    // L2: 1 x 4 x 32 = 128  -> [2560, 2688)
    // L3: 1 x 2 x 32 =  64  -> [2688, 2752)
    if (wid < 2048) {
        level_wave<512, 512, 9, 1>(yh0, y, wid, ws_acc, 0);
    } else if (wid < 2560) {
        level_wave<256, 256, 9, 2>(yh1, y, wid - 2048, ws_acc, 1);
    } else if (wid < 2688) {
        level_wave<128, 128, 7, 4>(yh2, y, wid - 2560, ws_acc, 2);
    } else {
        level_wave<64, 64, 5, 8>(yh3, y, wid - 2688, ws_acc, 3);
    }
}

__global__ void hier_finalize_kernel(const float* __restrict__ ws_acc, float* __restrict__ out)
{
    if (threadIdx.x == 0 && blockIdx.x == 0) {
        const float wts[4] = {1.0f, 0.5f, 0.25f, 0.125f};
        float total = 0.f;
#pragma unroll
        for (int lv = 0; lv < 4; ++lv) {
            float l2s = 0.f, ccs = 0.f;
            for (int s = 0; s < NSLOT; ++s) {
                l2s += ws_acc[(lv * 2 + 0) * NSLOT + s];
                ccs += ws_acc[(lv * 2 + 1) * NSLOT + s];
            }
            float l2  = l2s / 32.0f;
            float ncc = -ccs / (32.0f * 100.0f);
            float ll  = wts[lv] * (l2 + ncc) * 0.5f;
            out[1 + lv] = ll;
            total += ll;
        }
        out[0] = total;
    }
}

extern "C" void kernel_launch(void* const* d_in, const int* in_sizes, int n_in,
                              void* d_out, int out_size, void* d_ws, size_t ws_size,
                              hipStream_t stream)
{
    const float* yh0 = (const float*)d_in[0];
    const float* yh1 = (const float*)d_in[1];
    const float* yh2 = (const float*)d_in[2];
    const float* yh3 = (const float*)d_in[3];
    const float* y   = (const float*)d_in[4];
    float* ws_acc = (float*)d_ws;
    float* out = (float*)d_out;

    hipMemsetAsync(ws_acc, 0, 8 * NSLOT * sizeof(float), stream);
    hier_loss_kernel<<<2752 / (NT / 64), NT, 0, stream>>>(yh0, yh1, yh2, yh3, y, ws_acc);
    hier_finalize_kernel<<<1, 64, 0, stream>>>(ws_acc, out);
}

// Round 4
// 106.230 us; speedup vs baseline: 2.0687x; 2.0687x over previous
//
#include <hip/hip_runtime.h>

#define NT 256
#define RCHUNK 32
#define NSLOT 32
#define RWMAX (NT + 8)

__device__ __forceinline__ float ccval(float sI, float sJ, float sII, float sJJ,
                                       float sIJ, float inv_ws) {
    float cross = fmaf(-(sI * sJ), inv_ws, sIJ);
    float iv    = fmaf(-(sI * sI), inv_ws, sII);
    float jv    = fmaf(-(sJ * sJ), inv_ws, sJJ);
    float den   = fmaf(iv, jv, 1e-8f);
    return (cross * cross) * __builtin_amdgcn_rcpf(den);
}

struct St { float J, i0, i1, i2, i3; };

// Block = CW cols x RCHUNK rows of one image at one level. Thread = column.
// Raw rows double-buffered in LDS (1 barrier/row); 5-stat vertical sliding
// window ring lives in REGISTERS with compile-time slots (WIN-unrolled).
template<int W, int H, int WIN, int S, int CW>
__device__ __forceinline__ void level_block(const float* __restrict__ yh,
                                            const float* __restrict__ y,
                                            int sub, float* __restrict__ ws_acc,
                                            int level,
                                            float (*bufI)[RWMAX], float (*bufJ)[RWMAX])
{
    constexpr int HW  = WIN / 2;
    constexpr int RW  = CW + 2 * HW;
    constexpr int T   = RCHUNK + 2 * HW;
    constexpr int G   = (T + WIN - 1) / WIN;
    constexpr int NIT = G * WIN;
    constexpr int OFF = (S - 2) / 2;
    constexpr int WRAP = RW - NT;                 // #threads staging a 2nd element
    constexpr float INV_WS = 1.0f / (float)(WIN * WIN);

    constexpr int STRIPS = W / CW;
    constexpr int CHUNKS = H / RCHUNK;

    int b     = sub / (STRIPS * CHUNKS);
    int rem   = sub - b * (STRIPS * CHUNKS);
    int chunk = rem / STRIPS;
    int strip = rem - chunk * STRIPS;
    int r0 = chunk * RCHUNK;
    int c0 = strip * CW;

    const float* Jb = yh + (size_t)b * (W * H);
    const float* Yb = y  + (size_t)b * (512 * 512);

    int t  = threadIdx.x;
    int jA = c0 - HW + t;
    int jB = jA + NT;

    auto fetch = [&](int rr, int j, St& s) {
        s.J = 0.f; s.i0 = 0.f; s.i1 = 0.f; s.i2 = 0.f; s.i3 = 0.f;
        int r = r0 - HW + rr;
        if (rr < NIT && r >= 0 && r < H && j >= 0 && j < W) {
            s.J = Jb[(size_t)r * W + j];
            if constexpr (S == 1) {
                s.i0 = Yb[(size_t)r * 512 + j];
            } else {
                int yr = S * r + OFF;
                const float* p = Yb + (size_t)yr * 512 + (S * j + OFF);
                s.i0 = p[0]; s.i1 = p[1]; s.i2 = p[512]; s.i3 = p[513];
            }
        }
    };
    auto ival = [&](const St& s) -> float {
        if constexpr (S == 1) return s.i0;
        else return 0.25f * ((s.i0 + s.i1) + (s.i2 + s.i3));
    };

    // register ring of horizontal window sums (compile-time slots)
    float rI[WIN], rJ[WIN], rII[WIN], rJJ[WIN], rIJ[WIN];
#pragma unroll
    for (int k = 0; k < WIN; ++k) { rI[k]=0.f; rJ[k]=0.f; rII[k]=0.f; rJJ[k]=0.f; rIJ[k]=0.f; }
    float vI=0.f, vJ=0.f, vII=0.f, vJJ=0.f, vIJ=0.f;
    float l2acc = 0.f, ccacc = 0.f;

    St sA, sB;
    fetch(0, jA, sA);
    sB.J = 0.f; sB.i0 = 0.f; sB.i1 = 0.f; sB.i2 = 0.f; sB.i3 = 0.f;
    if constexpr (WRAP > 0) { if (t < WRAP) fetch(0, jB, sB); }

    for (int g = 0; g < G; ++g) {
#pragma unroll
        for (int u = 0; u < WIN; ++u) {
            int rr = g * WIN + u;
            float* bI = bufI[rr & 1];
            float* bJ = bufJ[rr & 1];

            // 1) write staged regs (row rr) to LDS
            bI[t] = ival(sA);
            bJ[t] = sA.J;
            if constexpr (WRAP > 0) {
                if (t < WRAP) { bI[t + NT] = ival(sB); bJ[t + NT] = sB.J; }
            }
            // 2) issue next row's global loads (latency hides under barrier+compute)
            fetch(rr + 1, jA, sA);
            if constexpr (WRAP > 0) { if (t < WRAP) fetch(rr + 1, jB, sB); }
            // 3) single barrier (double-buffered: WAR separated by previous barrier)
            __syncthreads();
            // 4) compute from LDS
            if (t < CW) {
                float sIs=0.f, sJs=0.f, sIIs=0.f, sJJs=0.f, sIJs=0.f, Ic=0.f, Jc=0.f;
#pragma unroll
                for (int k = 0; k < WIN; ++k) {
                    float I = bI[t + k];
                    float J = bJ[t + k];
                    if (k == HW) { Ic = I; Jc = J; }
                    sIs += I; sJs += J;
                    sIIs = fmaf(I, I, sIIs);
                    sJJs = fmaf(J, J, sJJs);
                    sIJs = fmaf(I, J, sIJs);
                }
                if (rr >= HW && rr < HW + RCHUNK) {
                    float d = Jc - Ic;
                    l2acc = fmaf(d, d, l2acc);
                }
                rI[u]=sIs; rJ[u]=sJs; rII[u]=sIIs; rJJ[u]=sJJs; rIJ[u]=sIJs;
                vI+=sIs; vJ+=sJs; vII+=sIIs; vJJ+=sJJs; vIJ+=sIJs;
                if (rr >= 2 * HW && rr < T) {
                    ccacc += ccval(vI, vJ, vII, vJJ, vIJ, INV_WS);
                    const int uo = (u + 1) % WIN;   // compile-time after unroll
                    vI-=rI[uo]; vJ-=rJ[uo]; vII-=rII[uo]; vJJ-=rJJ[uo]; vIJ-=rIJ[uo];
                }
            }
        }
    }

    // per-wave reduce + one atomic pair per wave (slot-spread)
#pragma unroll
    for (int off = 32; off > 0; off >>= 1) {
        l2acc += __shfl_down(l2acc, off);
        ccacc += __shfl_down(ccacc, off);
    }
    int lane = t & 63;
    if (lane == 0) {
        int slot = (blockIdx.x * 4 + (t >> 6)) & (NSLOT - 1);
        atomicAdd(&ws_acc[(level * 2 + 0) * NSLOT + slot], l2acc);
        atomicAdd(&ws_acc[(level * 2 + 1) * NSLOT + slot], ccacc);
    }
}

__global__ __launch_bounds__(NT)
void hier_loss_kernel(const float* __restrict__ yh0, const float* __restrict__ yh1,
                      const float* __restrict__ yh2, const float* __restrict__ yh3,
                      const float* __restrict__ y, float* ws_acc)
{
    __shared__ float bufI[2][RWMAX];
    __shared__ float bufJ[2][RWMAX];
    int bid = blockIdx.x;
    // L0: 2 strips x 16 chunks x 32 imgs = 1024 blocks
    // L1: 1 x 8 x 32 = 256  -> [1024, 1280)
    // L2: 1 x 4 x 32 = 128  -> [1280, 1408)
    // L3: 1 x 2 x 32 =  64  -> [1408, 1472)
    if (bid < 1024) {
        level_block<512, 512, 9, 1, 256>(yh0, y, bid, ws_acc, 0, bufI, bufJ);
    } else if (bid < 1280) {
        level_block<256, 256, 9, 2, 256>(yh1, y, bid - 1024, ws_acc, 1, bufI, bufJ);
    } else if (bid < 1408) {
        level_block<128, 128, 7, 4, 128>(yh2, y, bid - 1280, ws_acc, 2, bufI, bufJ);
    } else {
        level_block<64, 64, 5, 8, 64>(yh3, y, bid - 1408, ws_acc, 3, bufI, bufJ);
    }
}

__global__ void hier_finalize_kernel(const float* __restrict__ ws_acc, float* __restrict__ out)
{
    if (threadIdx.x == 0 && blockIdx.x == 0) {
        const float wts[4] = {1.0f, 0.5f, 0.25f, 0.125f};
        float total = 0.f;
#pragma unroll
        for (int lv = 0; lv < 4; ++lv) {
            float l2s = 0.f, ccs = 0.f;
            for (int s = 0; s < NSLOT; ++s) {
                l2s += ws_acc[(lv * 2 + 0) * NSLOT + s];
                ccs += ws_acc[(lv * 2 + 1) * NSLOT + s];
            }
            float l2  = l2s / 32.0f;
            float ncc = -ccs / (32.0f * 100.0f);
            float ll  = wts[lv] * (l2 + ncc) * 0.5f;
            out[1 + lv] = ll;
            total += ll;
        }
        out[0] = total;
    }
}

extern "C" void kernel_launch(void* const* d_in, const int* in_sizes, int n_in,
                              void* d_out, int out_size, void* d_ws, size_t ws_size,
                              hipStream_t stream)
{
    const float* yh0 = (const float*)d_in[0];
    const float* yh1 = (const float*)d_in[1];
    const float* yh2 = (const float*)d_in[2];
    const float* yh3 = (const float*)d_in[3];
    const float* y   = (const float*)d_in[4];
    float* ws_acc = (float*)d_ws;
    float* out = (float*)d_out;

    hipMemsetAsync(ws_acc, 0, 8 * NSLOT * sizeof(float), stream);
    hier_loss_kernel<<<1472, NT, 0, stream>>>(yh0, yh1, yh2, yh3, y, ws_acc);
    hier_finalize_kernel<<<1, 64, 0, stream>>>(ws_acc, out);
}